// Round 1
// 2438.363 us; speedup vs baseline: 1.0747x; 1.0747x over previous
//
#include <hip/hip_runtime.h>
#include <hip/hip_bf16.h>
#include <stdint.h>

#define N_ROWS 8192
#define DM     1024     // d_model
#define DS     16384    // d_sae
#define KTOP   64
#define CAND_CAP 256
#define KLIST_CAP 128

typedef __attribute__((ext_vector_type(8))) short bf16x8;
typedef __attribute__((ext_vector_type(4))) float f32x4;

#define AS1 __attribute__((address_space(1)))
#define AS3 __attribute__((address_space(3)))

// ---------------------------------------------------------------------------
// Kernel 1: transpose W_dec [DM x DS] -> Wt [DS x DM] (for coalesced decode)
// ---------------------------------------------------------------------------
__global__ __launch_bounds__(256) void transpose_wdec(const float* __restrict__ W,
                                                      float* __restrict__ Wt) {
    __shared__ float tile[32][33];
    const int tx = threadIdx.x;        // 0..31
    const int ty = threadIdx.y;        // 0..7
    const int s0 = blockIdx.x * 32;    // along DS
    const int d0 = blockIdx.y * 32;    // along DM
#pragma unroll
    for (int j = 0; j < 32; j += 8)
        tile[ty + j][tx] = W[(size_t)(d0 + ty + j) * DS + (s0 + tx)];
    __syncthreads();
#pragma unroll
    for (int j = 0; j < 32; j += 8)
        Wt[(size_t)(s0 + ty + j) * DM + (d0 + tx)] = tile[tx][ty + j];
}

// ---------------------------------------------------------------------------
// Kernel 2: split fp32 -> (bf16 hi, bf16 lo) in MFMA-staging packed layout.
// ---------------------------------------------------------------------------
__global__ __launch_bounds__(256) void pack_bf16(const float* __restrict__ src,
                                                 __hip_bfloat16* __restrict__ hi,
                                                 __hip_bfloat16* __restrict__ lo,
                                                 int nfrag) {
    const int t = blockIdx.x * 256 + threadIdx.x;
    if (t >= nfrag) return;
    const int l  = t & 63;
    const int g  = (t >> 6) & 7;
    const int ks = (t >> 9) & 31;
    const int rb = t >> 14;
    const int m = l & 15, q = l >> 4;
    const int row = rb * 128 + g * 16 + m;
    const int k0  = ks * 32 + q * 8;
    const float* s = src + (size_t)row * DM + k0;
#pragma unroll
    for (int j = 0; j < 8; ++j) {
        const float v = s[j];
        const __hip_bfloat16 hv = __float2bfloat16(v);
        const float r = v - __bfloat162float(hv);
        hi[(size_t)t * 8 + j] = hv;
        lo[(size_t)t * 8 + j] = __float2bfloat16(r);
    }
}

// ---------------------------------------------------------------------------
// Kernel 3: encoder GEMM via bf16x3 MFMA (Markidis split) — unchanged from
// the 2620us baseline; serves as the A/B control this round.
// ---------------------------------------------------------------------------
#define LDS_AHI 0
#define LDS_ALO 8192
#define LDS_BHI 16384
#define LDS_BLO 24576

__global__ __launch_bounds__(256) void enc_gemm_mfma(
        const __hip_bfloat16* __restrict__ xh, const __hip_bfloat16* __restrict__ xl,
        const __hip_bfloat16* __restrict__ wh, const __hip_bfloat16* __restrict__ wl,
        const float* __restrict__ bias, float* __restrict__ h) {
    __shared__ __align__(16) char lds[32768];
    const int tid  = threadIdx.x;
    const int lane = tid & 63;
    const int w    = tid >> 6;           // wave 0..3
    const int mb   = blockIdx.y;         // 0..63   (x row-block)
    const int sb   = blockIdx.x;         // 0..127  (W row-block)

    f32x4 acc[4][4];
#pragma unroll
    for (int i = 0; i < 4; ++i)
#pragma unroll
        for (int j = 0; j < 4; ++j) acc[i][j] = (f32x4){0.f, 0.f, 0.f, 0.f};

    const int gm = (w >> 1) * 4;   // this wave's A chunk base (m quadrant)
    const int gs = (w & 1) * 4;    // this wave's B chunk base (s quadrant)

    for (int ks = 0; ks < 32; ++ks) {
        const size_t abase = ((size_t)mb * 32 + ks) * 4096;
        const size_t bbase = ((size_t)sb * 32 + ks) * 4096;
#pragma unroll
        for (int c = 0; c < 2; ++c) {
            const int g = w * 2 + c;
            const size_t ao = abase + g * 512 + lane * 8;
            const size_t bo = bbase + g * 512 + lane * 8;
            __builtin_amdgcn_global_load_lds((const AS1 void*)(xh + ao),
                                             (AS3 void*)(lds + LDS_AHI + g * 1024), 16, 0, 0);
            __builtin_amdgcn_global_load_lds((const AS1 void*)(xl + ao),
                                             (AS3 void*)(lds + LDS_ALO + g * 1024), 16, 0, 0);
            __builtin_amdgcn_global_load_lds((const AS1 void*)(wh + bo),
                                             (AS3 void*)(lds + LDS_BHI + g * 1024), 16, 0, 0);
            __builtin_amdgcn_global_load_lds((const AS1 void*)(wl + bo),
                                             (AS3 void*)(lds + LDS_BLO + g * 1024), 16, 0, 0);
        }
        __syncthreads();

        bf16x8 ah[4], al[4], bh[4], bl[4];
#pragma unroll
        for (int t = 0; t < 4; ++t) {
            ah[t] = *((const bf16x8*)(lds + LDS_AHI + (gm + t) * 1024) + lane);
            al[t] = *((const bf16x8*)(lds + LDS_ALO + (gm + t) * 1024) + lane);
            bh[t] = *((const bf16x8*)(lds + LDS_BHI + (gs + t) * 1024) + lane);
            bl[t] = *((const bf16x8*)(lds + LDS_BLO + (gs + t) * 1024) + lane);
        }
#pragma unroll
        for (int tm = 0; tm < 4; ++tm)
#pragma unroll
            for (int ts = 0; ts < 4; ++ts) {
                acc[tm][ts] = __builtin_amdgcn_mfma_f32_16x16x32_bf16(ah[tm], bh[ts], acc[tm][ts], 0, 0, 0);
                acc[tm][ts] = __builtin_amdgcn_mfma_f32_16x16x32_bf16(ah[tm], bl[ts], acc[tm][ts], 0, 0, 0);
                acc[tm][ts] = __builtin_amdgcn_mfma_f32_16x16x32_bf16(al[tm], bh[ts], acc[tm][ts], 0, 0, 0);
            }
        __syncthreads();
    }

    const int m0 = mb * 128 + (w >> 1) * 64 + (lane >> 4) * 4;
    const int s0 = sb * 128 + (w & 1) * 64 + (lane & 15);
#pragma unroll
    for (int ts = 0; ts < 4; ++ts) {
        const int s = s0 + ts * 16;
        const float bb = bias[s];
#pragma unroll
        for (int tm = 0; tm < 4; ++tm) {
            const int m = m0 + tm * 16;
#pragma unroll
            for (int r = 0; r < 4; ++r)
                h[(size_t)(m + r) * DS + s] = fmaxf(acc[tm][ts][r] + bb, 0.0f);
        }
    }
}

// ---------------------------------------------------------------------------
// Kernel 2b: fp32 fallback GEMM if ws too small for packing
// ---------------------------------------------------------------------------
#define TM 128
#define TS 128
#define TK 16
#define LDP (TM + 4)

__global__ __launch_bounds__(256) void enc_gemm(const float* __restrict__ x,
                                                const float* __restrict__ W,
                                                const float* __restrict__ b,
                                                float* __restrict__ h) {
    __shared__ float As[TK][LDP];
    __shared__ float Ws[TK][LDP];
    const int tid  = threadIdx.x;
    const int tx   = tid & 15;
    const int ty   = tid >> 4;
    const int row0 = blockIdx.y * TM;
    const int s0   = blockIdx.x * TS;
    const int lm = tid >> 2;
    const int lk = (tid & 3) * 4;

    float acc[8][8];
#pragma unroll
    for (int i = 0; i < 8; ++i)
#pragma unroll
        for (int j = 0; j < 8; ++j) acc[i][j] = 0.0f;

    float4 a0 = *(const float4*)&x[(size_t)(row0 + lm) * DM + lk];
    float4 a1 = *(const float4*)&x[(size_t)(row0 + lm + 64) * DM + lk];
    float4 w0 = *(const float4*)&W[(size_t)(s0 + lm) * DM + lk];
    float4 w1 = *(const float4*)&W[(size_t)(s0 + lm + 64) * DM + lk];

    for (int k0 = 0; k0 < DM; k0 += TK) {
        __syncthreads();
        As[lk + 0][lm] = a0.x; As[lk + 1][lm] = a0.y;
        As[lk + 2][lm] = a0.z; As[lk + 3][lm] = a0.w;
        As[lk + 0][lm + 64] = a1.x; As[lk + 1][lm + 64] = a1.y;
        As[lk + 2][lm + 64] = a1.z; As[lk + 3][lm + 64] = a1.w;
        Ws[lk + 0][lm] = w0.x; Ws[lk + 1][lm] = w0.y;
        Ws[lk + 2][lm] = w0.z; Ws[lk + 3][lm] = w0.w;
        Ws[lk + 0][lm + 64] = w1.x; Ws[lk + 1][lm + 64] = w1.y;
        Ws[lk + 2][lm + 64] = w1.z; Ws[lk + 3][lm + 64] = w1.w;
        __syncthreads();
        const int kn = (k0 + TK < DM) ? (k0 + TK) : k0;
        a0 = *(const float4*)&x[(size_t)(row0 + lm) * DM + kn + lk];
        a1 = *(const float4*)&x[(size_t)(row0 + lm + 64) * DM + kn + lk];
        w0 = *(const float4*)&W[(size_t)(s0 + lm) * DM + kn + lk];
        w1 = *(const float4*)&W[(size_t)(s0 + lm + 64) * DM + kn + lk];
#pragma unroll
        for (int kk = 0; kk < TK; ++kk) {
            float4 aA = *(const float4*)&As[kk][ty * 4];
            float4 aB = *(const float4*)&As[kk][ty * 4 + 64];
            float4 wA = *(const float4*)&Ws[kk][tx * 4];
            float4 wB = *(const float4*)&Ws[kk][tx * 4 + 64];
            float am[8] = {aA.x, aA.y, aA.z, aA.w, aB.x, aB.y, aB.z, aB.w};
            float wn[8] = {wA.x, wA.y, wA.z, wA.w, wB.x, wB.y, wB.z, wB.w};
#pragma unroll
            for (int i = 0; i < 8; ++i)
#pragma unroll
                for (int j = 0; j < 8; ++j)
                    acc[i][j] = fmaf(am[i], wn[j], acc[i][j]);
        }
    }
    float blo[4], bhi[4];
#pragma unroll
    for (int u = 0; u < 4; ++u) {
        blo[u] = b[s0 + tx * 4 + u];
        bhi[u] = b[s0 + 64 + tx * 4 + u];
    }
#pragma unroll
    for (int i = 0; i < 8; ++i) {
        const int r = (i < 4) ? (row0 + ty * 4 + i) : (row0 + 64 + ty * 4 + (i - 4));
        float4 lo, hi;
        lo.x = fmaxf(acc[i][0] + blo[0], 0.0f);
        lo.y = fmaxf(acc[i][1] + blo[1], 0.0f);
        lo.z = fmaxf(acc[i][2] + blo[2], 0.0f);
        lo.w = fmaxf(acc[i][3] + blo[3], 0.0f);
        hi.x = fmaxf(acc[i][4] + bhi[0], 0.0f);
        hi.y = fmaxf(acc[i][5] + bhi[1], 0.0f);
        hi.z = fmaxf(acc[i][6] + bhi[2], 0.0f);
        hi.w = fmaxf(acc[i][7] + bhi[3], 0.0f);
        *(float4*)&h[(size_t)r * DS + s0 + tx * 4]      = lo;
        *(float4*)&h[(size_t)r * DS + s0 + 64 + tx * 4] = hi;
    }
}

// ---------------------------------------------------------------------------
// Kernel 4 (rewritten): per-row top-64 select + prune, fully LDS-staged.
//  - h row (64KB) staged in LDS once via float4; all radix/prune passes read
//    LDS (was: 5 global passes over 512MB).
//  - 8-way bank-interleaved histogram replicas cut same-bin LDS-atomic
//    serialization ~8x (pass 0 concentrates into ~7 exponent bins).
//  - wave-parallel bin selection (shfl suffix-scan) replaces the serial
//    256-iteration thread-0 scan.
//  - single vectorized row write-back (was: scattered zero stores).
//  - emits compact (idx,val) kept-list to workspace so decode never re-reads h.
// LDS: 64K row + 8K hist + ~8K scratch ~= 80KB -> 2 blocks/CU.
// ---------------------------------------------------------------------------
__global__ __launch_bounds__(256) void topk_select(const float* __restrict__ x,
                                                   const float* __restrict__ W,
                                                   const float* __restrict__ b,
                                                   float* __restrict__ h,
                                                   int* __restrict__ kidx_all,
                                                   float* __restrict__ kval_all,
                                                   int* __restrict__ kcnt_all,
                                                   const int use_list) {
    const int row = blockIdx.x;
    float* hrow = h + (size_t)row * DS;
    const int tid = threadIdx.x;

    __shared__ __align__(16) float sh[DS];     // 64 KB staged row
    __shared__ unsigned hist[256 * 8];         // 8-way replicated, bank-interleaved
    __shared__ unsigned sh_prefix;
    __shared__ int sh_k;
    __shared__ int kidx_s[KLIST_CAP];
    __shared__ float kval_s[KLIST_CAP];
    __shared__ int kcnt_s;
    __shared__ int cand_idx[CAND_CAP];
    __shared__ int cand_cnt;

    // ---- stage row into LDS ----
    {
        const float4* src = (const float4*)hrow;
        float4* dst = (float4*)sh;
        for (int i = tid; i < DS / 4; i += 256) dst[i] = src[i];
    }
    if (tid == 0) { sh_prefix = 0u; sh_k = KTOP; kcnt_s = 0; cand_cnt = 0; }
    __syncthreads();

    // ---- 4x8-bit radix threshold find, all from LDS ----
    const int rep = tid & 7;
    for (int pass = 0; pass < 4; ++pass) {
        const int shift = 24 - 8 * pass;
#pragma unroll
        for (int c8 = 0; c8 < 8; ++c8) hist[(tid << 3) + c8] = 0u;
        __syncthreads();
        const unsigned pfxv = sh_prefix;
        const int kv = sh_k;
        for (int i = tid; i < DS; i += 256) {
            const unsigned u = __float_as_uint(sh[i]);
            const bool ok = (pass == 0) || ((u >> (shift + 8)) == pfxv);
            if (ok) atomicAdd(&hist[(((u >> shift) & 255u) << 3) | rep], 1u);
        }
        __syncthreads();
        // wave 0: merge replicas + suffix-scan select (4 bins per lane)
        if (tid < 64) {
            unsigned b4[4];
            unsigned loc = 0;
#pragma unroll
            for (int jj = 0; jj < 4; ++jj) {
                const int bin = tid * 4 + jj;
                unsigned s = 0;
#pragma unroll
                for (int cc = 0; cc < 8; ++cc) s += hist[(bin << 3) + cc];
                b4[jj] = s;
                loc += s;
            }
            unsigned sfx = loc;   // inclusive suffix-sum across lanes
#pragma unroll
            for (int off = 1; off < 64; off <<= 1) {
                const unsigned o = __shfl_down(sfx, off, 64);
                if (tid + off < 64) sfx += o;
            }
            unsigned above = sfx - loc;   // count in bins strictly above my group
#pragma unroll
            for (int jj = 3; jj >= 0; --jj) {
                const unsigned c = b4[jj];
                if (above < (unsigned)kv && above + c >= (unsigned)kv) {
                    sh_k = kv - (int)above;
                    sh_prefix = (pfxv << 8) | (unsigned)(tid * 4 + jj);
                }
                above += c;
            }
        }
        __syncthreads();
    }

    const unsigned T = sh_prefix;

    // ---- T==0: fewer than KTOP positives; keep all, row untouched ----
    if (T == 0u) {
        if (use_list) {
            for (int i = tid; i < DS; i += 256) {
                const float v = sh[i];
                if (v != 0.0f) {
                    const int p = atomicAdd(&kcnt_s, 1);
                    if (p < KTOP) { kidx_s[p] = i; kval_s[p] = v; }
                }
            }
            __syncthreads();
            const int cnt = kcnt_s < KTOP ? kcnt_s : KTOP;
            if (tid == 0) kcnt_all[row] = cnt;
            for (int j = tid; j < cnt; j += 256) {
                kidx_all[(size_t)row * KTOP + j] = kidx_s[j];
                kval_all[(size_t)row * KTOP + j] = kval_s[j];
            }
        }
        return;
    }

    const float Tv = __uint_as_float(T);
    const float delta = (Tv > 0.01f) ? 2.5e-4f : 0.0f;
    const float loF = Tv - delta;
    const float hiF = Tv + delta;

    // ---- classify from LDS: sure-keep / boundary candidate / zero ----
    for (int i = tid; i < DS; i += 256) {
        const float v = sh[i];
        if (v > hiF) {
            const int p = atomicAdd(&kcnt_s, 1);
            if (p < KLIST_CAP) { kidx_s[p] = i; kval_s[p] = v; }
        } else if (v >= loF) {
            const int p = atomicAdd(&cand_cnt, 1);
            if (p < CAND_CAP) cand_idx[p] = i;
        } else if (v != 0.0f) {
            sh[i] = 0.0f;
        }
    }
    __syncthreads();

    const int sure = kcnt_s < KLIST_CAP ? kcnt_s : KLIST_CAP;
    const int nc = cand_cnt < CAND_CAP ? cand_cnt : CAND_CAP;
    const int need = KTOP - sure;

    if (nc <= need) {
        // keep all boundary candidates
        for (int j = tid; j < nc; j += 256) {
            const int p = sure + j;
            if (p < KLIST_CAP) { kidx_s[p] = cand_idx[j]; kval_s[p] = sh[cand_idx[j]]; }
        }
        if (tid == 0) kcnt_s = sure + nc;
        __syncthreads();
    } else {
        // fp64 exact recompute of boundary band
        __shared__ double cand_val[CAND_CAP];
        __shared__ double red[256];
        const float* xrow = x + (size_t)row * DM;
        for (int j = 0; j < nc; ++j) {
            const float* wrow = W + (size_t)cand_idx[j] * DM;
            const int kk = tid * 4;
            double s = (double)xrow[kk + 0] * (double)wrow[kk + 0]
                     + (double)xrow[kk + 1] * (double)wrow[kk + 1]
                     + (double)xrow[kk + 2] * (double)wrow[kk + 2]
                     + (double)xrow[kk + 3] * (double)wrow[kk + 3];
            red[tid] = s;
            __syncthreads();
            for (int off = 128; off > 0; off >>= 1) {
                if (tid < off) red[tid] += red[tid + off];
                __syncthreads();
            }
            if (tid == 0) cand_val[j] = red[0] + (double)b[cand_idx[j]];
            __syncthreads();
        }
        if (tid == 0) {
            bool keep[CAND_CAP];
            for (int j = 0; j < nc; ++j) keep[j] = false;
            for (int t = 0; t < need; ++t) {
                int best = -1;
                for (int j = 0; j < nc; ++j) {
                    if (keep[j]) continue;
                    if (best < 0 || cand_val[j] > cand_val[best] ||
                        (cand_val[j] == cand_val[best] && cand_idx[j] < cand_idx[best]))
                        best = j;
                }
                keep[best] = true;
            }
            int kc = sure;
            for (int j = 0; j < nc; ++j) {
                if (keep[j]) {
                    if (kc < KLIST_CAP) { kidx_s[kc] = cand_idx[j]; kval_s[kc] = sh[cand_idx[j]]; }
                    ++kc;
                } else {
                    sh[cand_idx[j]] = 0.0f;
                }
            }
            kcnt_s = kc;
        }
        __syncthreads();
    }

    // ---- single vectorized write-back of pruned row ----
    {
        const float4* srcv = (const float4*)sh;
        float4* dstv = (float4*)hrow;
        for (int i = tid; i < DS / 4; i += 256) dstv[i] = srcv[i];
    }

    if (use_list) {
        const int cnt = kcnt_s < KTOP ? kcnt_s : KTOP;
        if (tid == 0) kcnt_all[row] = cnt;
        for (int j = tid; j < cnt; j += 256) {
            kidx_all[(size_t)row * KTOP + j] = kidx_s[j];
            kval_all[(size_t)row * KTOP + j] = kval_s[j];
        }
    }
}

// ---------------------------------------------------------------------------
// Kernel 5a: sparse decode from compact list (no h re-read)
// ---------------------------------------------------------------------------
__global__ __launch_bounds__(256) void decode_list(const int* __restrict__ kcnt_all,
                                                   const int* __restrict__ kidx_all,
                                                   const float* __restrict__ kval_all,
                                                   const float* __restrict__ Wt,
                                                   float* __restrict__ recon) {
    const int row = blockIdx.x;
    const int tid = threadIdx.x;

    __shared__ int   s_idx[KTOP];
    __shared__ float s_val[KTOP];
    __shared__ int   s_cnt;

    if (tid == 0) s_cnt = kcnt_all[row];
    if (tid < KTOP) {
        s_idx[tid] = kidx_all[(size_t)row * KTOP + tid];
        s_val[tid] = kval_all[(size_t)row * KTOP + tid];
    }
    __syncthreads();
    const int cnt = s_cnt;

    const int d = tid * 4;
    float4 acc = {0.0f, 0.0f, 0.0f, 0.0f};
    for (int j = 0; j < cnt; ++j) {
        const float v = s_val[j];
        const float4 w = *(const float4*)&Wt[(size_t)s_idx[j] * DM + d];
        acc.x = fmaf(v, w.x, acc.x);
        acc.y = fmaf(v, w.y, acc.y);
        acc.z = fmaf(v, w.z, acc.z);
        acc.w = fmaf(v, w.w, acc.w);
    }
    *(float4*)&recon[(size_t)row * DM + d] = acc;
}

// ---------------------------------------------------------------------------
// Kernel 5b: fallback decode (scans h) if ws too small for the list
// ---------------------------------------------------------------------------
__global__ __launch_bounds__(256) void decode(const float* __restrict__ h,
                                              const float* __restrict__ Wt,
                                              const float* __restrict__ Wdec,
                                              const int use_wt,
                                              float* __restrict__ recon) {
    const int row = blockIdx.x;
    const float* hrow = h + (size_t)row * DS;
    const int tid = threadIdx.x;

    __shared__ int   s_idx[KTOP];
    __shared__ float s_val[KTOP];
    __shared__ int   s_cnt;

    if (tid == 0) s_cnt = 0;
    __syncthreads();
    for (int i = tid; i < DS; i += 256) {
        const float v = hrow[i];
        if (v != 0.0f) {
            const int p = atomicAdd(&s_cnt, 1);
            if (p < KTOP) { s_idx[p] = i; s_val[p] = v; }
        }
    }
    __syncthreads();
    const int cnt = s_cnt < KTOP ? s_cnt : KTOP;

    const int d = tid * 4;
    float4 acc = {0.0f, 0.0f, 0.0f, 0.0f};
    if (use_wt) {
        for (int j = 0; j < cnt; ++j) {
            const float v = s_val[j];
            const float4 w = *(const float4*)&Wt[(size_t)s_idx[j] * DM + d];
            acc.x = fmaf(v, w.x, acc.x);
            acc.y = fmaf(v, w.y, acc.y);
            acc.z = fmaf(v, w.z, acc.z);
            acc.w = fmaf(v, w.w, acc.w);
        }
    } else {
        for (int j = 0; j < cnt; ++j) {
            const float v = s_val[j];
            const int s = s_idx[j];
            acc.x = fmaf(v, Wdec[(size_t)(d + 0) * DS + s], acc.x);
            acc.y = fmaf(v, Wdec[(size_t)(d + 1) * DS + s], acc.y);
            acc.z = fmaf(v, Wdec[(size_t)(d + 2) * DS + s], acc.z);
            acc.w = fmaf(v, Wdec[(size_t)(d + 3) * DS + s], acc.w);
        }
    }
    *(float4*)&recon[(size_t)row * DM + d] = acc;
}

// ---------------------------------------------------------------------------
extern "C" void kernel_launch(void* const* d_in, const int* in_sizes, int n_in,
                              void* d_out, int out_size, void* d_ws, size_t ws_size,
                              hipStream_t stream) {
    const float* x     = (const float*)d_in[0];
    const float* W_enc = (const float*)d_in[1];
    const float* b_enc = (const float*)d_in[2];
    const float* W_dec = (const float*)d_in[3];

    float* recon = (float*)d_out;
    float* h     = recon + (size_t)N_ROWS * DM;

    // workspace layout
    const size_t WT_BYTES = (size_t)DS * DM * sizeof(float);              // 64 MB
    const size_t XP_BYTES = (size_t)N_ROWS * DM * sizeof(__hip_bfloat16); // 16 MB
    const size_t WP_BYTES = (size_t)DS * DM * sizeof(__hip_bfloat16);     // 32 MB
    const size_t FULL_NEED = WT_BYTES + 2 * XP_BYTES + 2 * WP_BYTES;      // 160 MB
    const size_t KIDX_BYTES = (size_t)N_ROWS * KTOP * sizeof(int);        // 2 MB
    const size_t KVAL_BYTES = (size_t)N_ROWS * KTOP * sizeof(float);      // 2 MB
    const size_t KCNT_BYTES = (size_t)N_ROWS * sizeof(int);               // 32 KB
    const size_t LIST_NEED = FULL_NEED + KIDX_BYTES + KVAL_BYTES + KCNT_BYTES;

    char* wsb = (char*)d_ws;
    float* Wt = (float*)wsb;
    __hip_bfloat16* xhi = (__hip_bfloat16*)(wsb + WT_BYTES);
    __hip_bfloat16* xlo = (__hip_bfloat16*)(wsb + WT_BYTES + XP_BYTES);
    __hip_bfloat16* whi = (__hip_bfloat16*)(wsb + WT_BYTES + 2 * XP_BYTES);
    __hip_bfloat16* wlo = (__hip_bfloat16*)(wsb + WT_BYTES + 2 * XP_BYTES + WP_BYTES);
    int*   kidx_all = (int*)(wsb + FULL_NEED);
    float* kval_all = (float*)(wsb + FULL_NEED + KIDX_BYTES);
    int*   kcnt_all = (int*)(wsb + FULL_NEED + KIDX_BYTES + KVAL_BYTES);

    const int use_wt   = (ws_size >= WT_BYTES) ? 1 : 0;
    const int use_mfma = (ws_size >= FULL_NEED) ? 1 : 0;
    const int use_list = (ws_size >= LIST_NEED) ? 1 : 0;

    if (use_wt) {
        transpose_wdec<<<dim3(DS / 32, DM / 32), dim3(32, 8), 0, stream>>>(W_dec, Wt);
    }
    if (use_mfma) {
        const int nfrag_x = N_ROWS * DM / 8;   // 1048576
        const int nfrag_w = DS * DM / 8;       // 2097152
        pack_bf16<<<nfrag_x / 256, 256, 0, stream>>>(x, xhi, xlo, nfrag_x);
        pack_bf16<<<nfrag_w / 256, 256, 0, stream>>>(W_enc, whi, wlo, nfrag_w);
        enc_gemm_mfma<<<dim3(DS / 128, N_ROWS / 128), 256, 0, stream>>>(
            xhi, xlo, whi, wlo, b_enc, h);
    } else {
        enc_gemm<<<dim3(DS / TS, N_ROWS / TM), 256, 0, stream>>>(x, W_enc, b_enc, h);
    }
    topk_select<<<N_ROWS, 256, 0, stream>>>(x, W_enc, b_enc, h,
                                            kidx_all, kval_all, kcnt_all, use_list);
    if (use_list) {
        decode_list<<<N_ROWS, 256, 0, stream>>>(kcnt_all, kidx_all, kval_all, Wt, recon);
    } else {
        decode<<<N_ROWS, 256, 0, stream>>>(h, Wt, W_dec, use_wt, recon);
    }
}

// Round 2
// 1813.474 us; speedup vs baseline: 1.4450x; 1.3446x over previous
//
#include <hip/hip_runtime.h>
#include <hip/hip_bf16.h>
#include <stdint.h>

#define N_ROWS 8192
#define DM     1024     // d_model
#define DS     16384    // d_sae
#define KTOP   64
#define CAND_CAP 256

typedef __attribute__((ext_vector_type(8))) short bf16x8;
typedef __attribute__((ext_vector_type(4))) float f32x4;

#define AS1 __attribute__((address_space(1)))
#define AS3 __attribute__((address_space(3)))

// ---------------------------------------------------------------------------
// Kernel 1: transpose W_dec [DM x DS] -> Wt fp32 [DS x DM] (fallback path)
// ---------------------------------------------------------------------------
__global__ __launch_bounds__(256) void transpose_wdec(const float* __restrict__ W,
                                                      float* __restrict__ Wt) {
    __shared__ float tile[32][33];
    const int tx = threadIdx.x;        // 0..31
    const int ty = threadIdx.y;        // 0..7
    const int s0 = blockIdx.x * 32;    // along DS
    const int d0 = blockIdx.y * 32;    // along DM
#pragma unroll
    for (int j = 0; j < 32; j += 8)
        tile[ty + j][tx] = W[(size_t)(d0 + ty + j) * DS + (s0 + tx)];
    __syncthreads();
#pragma unroll
    for (int j = 0; j < 32; j += 8)
        Wt[(size_t)(s0 + ty + j) * DM + (d0 + tx)] = tile[tx][ty + j];
}

// ---------------------------------------------------------------------------
// Kernel 1b: transpose W_dec -> Wtb bf16 [DS x DM] (halves decode gather bytes)
// ---------------------------------------------------------------------------
__global__ __launch_bounds__(256) void transpose_wdec_bf16(const float* __restrict__ W,
                                                           __hip_bfloat16* __restrict__ Wtb) {
    __shared__ float tile[32][33];
    const int tx = threadIdx.x;        // 0..31
    const int ty = threadIdx.y;        // 0..7
    const int tid = ty * 32 + tx;
    const int s0 = blockIdx.x * 32;    // along DS
    const int d0 = blockIdx.y * 32;    // along DM
#pragma unroll
    for (int j = 0; j < 32; j += 8)
        tile[ty + j][tx] = W[(size_t)(d0 + ty + j) * DS + (s0 + tx)];
    __syncthreads();
    // write ushort2 pairs for 4B-coalesced stores
    const int cp = tid & 15;           // column pair within d
    const int rr = tid >> 4;           // 0..15 (s rows)
#pragma unroll
    for (int j = 0; j < 32; j += 16) {
        const int sl = rr + j;
        __hip_bfloat162 pr;
        pr.x = __float2bfloat16(tile[cp * 2 + 0][sl]);
        pr.y = __float2bfloat16(tile[cp * 2 + 1][sl]);
        *(__hip_bfloat162*)(Wtb + (size_t)(s0 + sl) * DM + d0 + cp * 2) = pr;
    }
}

// ---------------------------------------------------------------------------
// Kernel 2: split fp32 -> (bf16 hi, bf16 lo) in MFMA-staging packed layout.
// ---------------------------------------------------------------------------
__global__ __launch_bounds__(256) void pack_bf16(const float* __restrict__ src,
                                                 __hip_bfloat16* __restrict__ hi,
                                                 __hip_bfloat16* __restrict__ lo,
                                                 int nfrag) {
    const int t = blockIdx.x * 256 + threadIdx.x;
    if (t >= nfrag) return;
    const int l  = t & 63;
    const int g  = (t >> 6) & 7;
    const int ks = (t >> 9) & 31;
    const int rb = t >> 14;
    const int m = l & 15, q = l >> 4;
    const int row = rb * 128 + g * 16 + m;
    const int k0  = ks * 32 + q * 8;
    const float* s = src + (size_t)row * DM + k0;
#pragma unroll
    for (int j = 0; j < 8; ++j) {
        const float v = s[j];
        const __hip_bfloat16 hv = __float2bfloat16(v);
        const float r = v - __bfloat162float(hv);
        hi[(size_t)t * 8 + j] = hv;
        lo[(size_t)t * 8 + j] = __float2bfloat16(r);
    }
}

// ---------------------------------------------------------------------------
// Kernel 3: encoder GEMM via bf16x3 MFMA (Markidis split) — unchanged control.
// ---------------------------------------------------------------------------
#define LDS_AHI 0
#define LDS_ALO 8192
#define LDS_BHI 16384
#define LDS_BLO 24576

__global__ __launch_bounds__(256) void enc_gemm_mfma(
        const __hip_bfloat16* __restrict__ xh, const __hip_bfloat16* __restrict__ xl,
        const __hip_bfloat16* __restrict__ wh, const __hip_bfloat16* __restrict__ wl,
        const float* __restrict__ bias, float* __restrict__ h) {
    __shared__ __align__(16) char lds[32768];
    const int tid  = threadIdx.x;
    const int lane = tid & 63;
    const int w    = tid >> 6;           // wave 0..3
    const int mb   = blockIdx.y;         // 0..63   (x row-block)
    const int sb   = blockIdx.x;         // 0..127  (W row-block)

    f32x4 acc[4][4];
#pragma unroll
    for (int i = 0; i < 4; ++i)
#pragma unroll
        for (int j = 0; j < 4; ++j) acc[i][j] = (f32x4){0.f, 0.f, 0.f, 0.f};

    const int gm = (w >> 1) * 4;   // this wave's A chunk base (m quadrant)
    const int gs = (w & 1) * 4;    // this wave's B chunk base (s quadrant)

    for (int ks = 0; ks < 32; ++ks) {
        const size_t abase = ((size_t)mb * 32 + ks) * 4096;
        const size_t bbase = ((size_t)sb * 32 + ks) * 4096;
#pragma unroll
        for (int c = 0; c < 2; ++c) {
            const int g = w * 2 + c;
            const size_t ao = abase + g * 512 + lane * 8;
            const size_t bo = bbase + g * 512 + lane * 8;
            __builtin_amdgcn_global_load_lds((const AS1 void*)(xh + ao),
                                             (AS3 void*)(lds + LDS_AHI + g * 1024), 16, 0, 0);
            __builtin_amdgcn_global_load_lds((const AS1 void*)(xl + ao),
                                             (AS3 void*)(lds + LDS_ALO + g * 1024), 16, 0, 0);
            __builtin_amdgcn_global_load_lds((const AS1 void*)(wh + bo),
                                             (AS3 void*)(lds + LDS_BHI + g * 1024), 16, 0, 0);
            __builtin_amdgcn_global_load_lds((const AS1 void*)(wl + bo),
                                             (AS3 void*)(lds + LDS_BLO + g * 1024), 16, 0, 0);
        }
        __syncthreads();

        bf16x8 ah[4], al[4], bh[4], bl[4];
#pragma unroll
        for (int t = 0; t < 4; ++t) {
            ah[t] = *((const bf16x8*)(lds + LDS_AHI + (gm + t) * 1024) + lane);
            al[t] = *((const bf16x8*)(lds + LDS_ALO + (gm + t) * 1024) + lane);
            bh[t] = *((const bf16x8*)(lds + LDS_BHI + (gs + t) * 1024) + lane);
            bl[t] = *((const bf16x8*)(lds + LDS_BLO + (gs + t) * 1024) + lane);
        }
#pragma unroll
        for (int tm = 0; tm < 4; ++tm)
#pragma unroll
            for (int ts = 0; ts < 4; ++ts) {
                acc[tm][ts] = __builtin_amdgcn_mfma_f32_16x16x32_bf16(ah[tm], bh[ts], acc[tm][ts], 0, 0, 0);
                acc[tm][ts] = __builtin_amdgcn_mfma_f32_16x16x32_bf16(ah[tm], bl[ts], acc[tm][ts], 0, 0, 0);
                acc[tm][ts] = __builtin_amdgcn_mfma_f32_16x16x32_bf16(al[tm], bh[ts], acc[tm][ts], 0, 0, 0);
            }
        __syncthreads();
    }

    const int m0 = mb * 128 + (w >> 1) * 64 + (lane >> 4) * 4;
    const int s0 = sb * 128 + (w & 1) * 64 + (lane & 15);
#pragma unroll
    for (int ts = 0; ts < 4; ++ts) {
        const int s = s0 + ts * 16;
        const float bb = bias[s];
#pragma unroll
        for (int tm = 0; tm < 4; ++tm) {
            const int m = m0 + tm * 16;
#pragma unroll
            for (int r = 0; r < 4; ++r)
                h[(size_t)(m + r) * DS + s] = fmaxf(acc[tm][ts][r] + bb, 0.0f);
        }
    }
}

// ---------------------------------------------------------------------------
// Kernel 2b: fp32 fallback GEMM if ws too small for packing
// ---------------------------------------------------------------------------
#define TM 128
#define TS 128
#define TK 16
#define LDP (TM + 4)

__global__ __launch_bounds__(256) void enc_gemm(const float* __restrict__ x,
                                                const float* __restrict__ W,
                                                const float* __restrict__ b,
                                                float* __restrict__ h) {
    __shared__ float As[TK][LDP];
    __shared__ float Ws[TK][LDP];
    const int tid  = threadIdx.x;
    const int tx   = tid & 15;
    const int ty   = tid >> 4;
    const int row0 = blockIdx.y * TM;
    const int s0   = blockIdx.x * TS;
    const int lm = tid >> 2;
    const int lk = (tid & 3) * 4;

    float acc[8][8];
#pragma unroll
    for (int i = 0; i < 8; ++i)
#pragma unroll
        for (int j = 0; j < 8; ++j) acc[i][j] = 0.0f;

    float4 a0 = *(const float4*)&x[(size_t)(row0 + lm) * DM + lk];
    float4 a1 = *(const float4*)&x[(size_t)(row0 + lm + 64) * DM + lk];
    float4 w0 = *(const float4*)&W[(size_t)(s0 + lm) * DM + lk];
    float4 w1 = *(const float4*)&W[(size_t)(s0 + lm + 64) * DM + lk];

    for (int k0 = 0; k0 < DM; k0 += TK) {
        __syncthreads();
        As[lk + 0][lm] = a0.x; As[lk + 1][lm] = a0.y;
        As[lk + 2][lm] = a0.z; As[lk + 3][lm] = a0.w;
        As[lk + 0][lm + 64] = a1.x; As[lk + 1][lm + 64] = a1.y;
        As[lk + 2][lm + 64] = a1.z; As[lk + 3][lm + 64] = a1.w;
        Ws[lk + 0][lm] = w0.x; Ws[lk + 1][lm] = w0.y;
        Ws[lk + 2][lm] = w0.z; Ws[lk + 3][lm] = w0.w;
        Ws[lk + 0][lm + 64] = w1.x; Ws[lk + 1][lm + 64] = w1.y;
        Ws[lk + 2][lm + 64] = w1.z; Ws[lk + 3][lm + 64] = w1.w;
        __syncthreads();
        const int kn = (k0 + TK < DM) ? (k0 + TK) : k0;
        a0 = *(const float4*)&x[(size_t)(row0 + lm) * DM + kn + lk];
        a1 = *(const float4*)&x[(size_t)(row0 + lm + 64) * DM + kn + lk];
        w0 = *(const float4*)&W[(size_t)(s0 + lm) * DM + kn + lk];
        w1 = *(const float4*)&W[(size_t)(s0 + lm + 64) * DM + kn + lk];
#pragma unroll
        for (int kk = 0; kk < TK; ++kk) {
            float4 aA = *(const float4*)&As[kk][ty * 4];
            float4 aB = *(const float4*)&As[kk][ty * 4 + 64];
            float4 wA = *(const float4*)&Ws[kk][tx * 4];
            float4 wB = *(const float4*)&Ws[kk][tx * 4 + 64];
            float am[8] = {aA.x, aA.y, aA.z, aA.w, aB.x, aB.y, aB.z, aB.w};
            float wn[8] = {wA.x, wA.y, wA.z, wA.w, wB.x, wB.y, wB.z, wB.w};
#pragma unroll
            for (int i = 0; i < 8; ++i)
#pragma unroll
                for (int j = 0; j < 8; ++j)
                    acc[i][j] = fmaf(am[i], wn[j], acc[i][j]);
        }
    }
    float blo[4], bhi[4];
#pragma unroll
    for (int u = 0; u < 4; ++u) {
        blo[u] = b[s0 + tx * 4 + u];
        bhi[u] = b[s0 + 64 + tx * 4 + u];
    }
#pragma unroll
    for (int i = 0; i < 8; ++i) {
        const int r = (i < 4) ? (row0 + ty * 4 + i) : (row0 + 64 + ty * 4 + (i - 4));
        float4 lo, hi;
        lo.x = fmaxf(acc[i][0] + blo[0], 0.0f);
        lo.y = fmaxf(acc[i][1] + blo[1], 0.0f);
        lo.z = fmaxf(acc[i][2] + blo[2], 0.0f);
        lo.w = fmaxf(acc[i][3] + blo[3], 0.0f);
        hi.x = fmaxf(acc[i][4] + bhi[0], 0.0f);
        hi.y = fmaxf(acc[i][5] + bhi[1], 0.0f);
        hi.z = fmaxf(acc[i][6] + bhi[2], 0.0f);
        hi.w = fmaxf(acc[i][7] + bhi[3], 0.0f);
        *(float4*)&h[(size_t)r * DS + s0 + tx * 4]      = lo;
        *(float4*)&h[(size_t)r * DS + s0 + 64 + tx * 4] = hi;
    }
}

// ---------------------------------------------------------------------------
// radix bin selection by one wave: bins ascending in value; find bin holding
// the kv-th largest, rank within bin, and (optionally) whether total < kv.
// ---------------------------------------------------------------------------
template <int PER_LANE>
__device__ inline void radix_select(const unsigned* __restrict__ hist,
                                    int lane, int kv,
                                    unsigned* sel_bin, int* sel_k, int* lt_flag) {
    unsigned cnt[PER_LANE];
    unsigned loc = 0;
#pragma unroll
    for (int j = 0; j < PER_LANE; ++j) { cnt[j] = hist[lane * PER_LANE + j]; loc += cnt[j]; }
    unsigned sfx = loc;
#pragma unroll
    for (int off = 1; off < 64; off <<= 1) {
        const unsigned o = __shfl_down(sfx, off, 64);
        if (lane + off < 64) sfx += o;
    }
    if (lt_flag != nullptr && lane == 0 && sfx < (unsigned)kv) *lt_flag = 1;
    unsigned above = sfx - loc;     // values in strictly higher lanes' bins
#pragma unroll
    for (int j = PER_LANE - 1; j >= 0; --j) {
        const unsigned c = cnt[j];
        if (above < (unsigned)kv && above + c >= (unsigned)kv) {
            *sel_k = kv - (int)above;
            *sel_bin = (unsigned)(lane * PER_LANE + j);
        }
        above += c;
    }
}

// ---------------------------------------------------------------------------
// Kernel 4 (register version): per-row top-64 select + prune.
//  - 512 threads; each holds 32 row values in 8 x f32x4 registers (static idx).
//  - 3-pass radix (11/11/10 bits) on 2048-bin LDS hist; pass 1 fused w/ load;
//    passes 2/3 filter from registers (near-zero atomic traffic).
//  - zero-skip removes the ~8K same-address bin-0 atomics per row.
//  - LDS ~12 KB (was 78 KB) -> occupancy VGPR-bound (~24 waves/CU vs 8).
//  - identical selection semantics: exact 32-bit T, +/-2.5e-4 band, fp64
//    boundary resolve, CAND_CAP overflow behavior preserved.
// ---------------------------------------------------------------------------
__global__ __launch_bounds__(512) void topk_select(const float* __restrict__ x,
                                                   const float* __restrict__ W,
                                                   const float* __restrict__ b,
                                                   float* __restrict__ h,
                                                   int* __restrict__ kidx_all,
                                                   float* __restrict__ kval_all,
                                                   int* __restrict__ kcnt_all,
                                                   const int use_list) {
    const int row = blockIdx.x;
    float* hrow = h + (size_t)row * DS;
    const int tid  = threadIdx.x;
    const int lane = tid & 63;

    __shared__ unsigned hist[2048];
    __shared__ unsigned sel_bin;
    __shared__ int sel_k;
    __shared__ int lt_flag;
    __shared__ int kidx_s[KTOP];
    __shared__ float kval_s[KTOP];
    __shared__ int kcnt_s;
    __shared__ int cand_idx[CAND_CAP];
    __shared__ int cand_cnt;
    __shared__ double cand_val[CAND_CAP];
    __shared__ unsigned char cand_keep[CAND_CAP];
    __shared__ double redw[8];

    hist[tid] = 0u; hist[tid + 512] = 0u; hist[tid + 1024] = 0u; hist[tid + 1536] = 0u;
    if (tid == 0) { sel_k = KTOP; kcnt_s = 0; cand_cnt = 0; lt_flag = 0; }
    __syncthreads();

    // ---- load row into registers + pass-1 histogram (top 11 bits) ----
    const f32x4* src = (const f32x4*)hrow;
    f32x4 v[8];
#pragma unroll
    for (int i = 0; i < 8; ++i) v[i] = src[tid + i * 512];
#pragma unroll
    for (int i = 0; i < 8; ++i)
#pragma unroll
        for (int c = 0; c < 4; ++c) {
            const unsigned u = __float_as_uint(v[i][c]);
            if (u != 0u) atomicAdd(&hist[u >> 21], 1u);
        }
    __syncthreads();
    if (tid < 64) radix_select<32>(hist, lane, KTOP, &sel_bin, &sel_k, &lt_flag);
    __syncthreads();

    // ---- fewer than KTOP positives: keep everything, row already correct ----
    if (lt_flag != 0) {
        if (use_list) {
#pragma unroll
            for (int i = 0; i < 8; ++i)
#pragma unroll
                for (int c = 0; c < 4; ++c) {
                    const float vv = v[i][c];
                    if (vv != 0.0f) {
                        const int p = atomicAdd(&kcnt_s, 1);
                        if (p < KTOP) { kidx_s[p] = (tid + i * 512) * 4 + c; kval_s[p] = vv; }
                    }
                }
            __syncthreads();
            const int cnt = kcnt_s < KTOP ? kcnt_s : KTOP;
            if (tid == 0) kcnt_all[row] = cnt;
            for (int j = tid; j < cnt; j += 512) {
                kidx_all[(size_t)row * KTOP + j] = kidx_s[j];
                kval_all[(size_t)row * KTOP + j] = kval_s[j];
            }
        }
        return;
    }

    const unsigned b1 = sel_bin;

    // ---- pass 2: next 11 bits among bin-b1 values ----
    hist[tid] = 0u; hist[tid + 512] = 0u; hist[tid + 1024] = 0u; hist[tid + 1536] = 0u;
    __syncthreads();
#pragma unroll
    for (int i = 0; i < 8; ++i)
#pragma unroll
        for (int c = 0; c < 4; ++c) {
            const unsigned u = __float_as_uint(v[i][c]);
            if (u != 0u && (u >> 21) == b1) atomicAdd(&hist[(u >> 10) & 0x7FFu], 1u);
        }
    __syncthreads();
    {
        const int kv = sel_k;
        if (tid < 64) radix_select<32>(hist, lane, kv, &sel_bin, &sel_k, nullptr);
    }
    __syncthreads();
    const unsigned pfx22 = (b1 << 11) | sel_bin;

    // ---- pass 3: final 10 bits ----
    hist[tid] = 0u; hist[tid + 512] = 0u;
    __syncthreads();
#pragma unroll
    for (int i = 0; i < 8; ++i)
#pragma unroll
        for (int c = 0; c < 4; ++c) {
            const unsigned u = __float_as_uint(v[i][c]);
            if (u != 0u && (u >> 10) == pfx22) atomicAdd(&hist[u & 0x3FFu], 1u);
        }
    __syncthreads();
    {
        const int kv = sel_k;
        if (tid < 64) radix_select<16>(hist, lane, kv, &sel_bin, &sel_k, nullptr);
    }
    __syncthreads();
    const unsigned T = (pfx22 << 10) | sel_bin;

    const float Tv = __uint_as_float(T);
    const float delta = (Tv > 0.01f) ? 2.5e-4f : 0.0f;
    const float loF = Tv - delta;
    const float hiF = Tv + delta;

    // ---- classify from registers ----
#pragma unroll
    for (int i = 0; i < 8; ++i)
#pragma unroll
        for (int c = 0; c < 4; ++c) {
            const float vv = v[i][c];
            if (vv > hiF) {
                const int p = atomicAdd(&kcnt_s, 1);
                if (p < KTOP) { kidx_s[p] = (tid + i * 512) * 4 + c; kval_s[p] = vv; }
            } else if (vv >= loF) {
                const int p = atomicAdd(&cand_cnt, 1);
                if (p < CAND_CAP) cand_idx[p] = (tid + i * 512) * 4 + c;
            } else if (vv != 0.0f) {
                v[i][c] = 0.0f;
            }
        }
    __syncthreads();

    const int sure = kcnt_s < KTOP ? kcnt_s : KTOP;
    const int nc = cand_cnt < CAND_CAP ? cand_cnt : CAND_CAP;
    const int need = KTOP - sure;

    if (nc > need) {
        // fp64 exact recompute of boundary band
        const float* xrow = x + (size_t)row * DM;
        const int kk = tid * 2;
        const double x0 = (double)xrow[kk], x1 = (double)xrow[kk + 1];
        for (int j = 0; j < nc; ++j) {
            const float* wrow = W + (size_t)cand_idx[j] * DM;
            double s = x0 * (double)wrow[kk] + x1 * (double)wrow[kk + 1];
#pragma unroll
            for (int off = 32; off > 0; off >>= 1)
                s += __shfl_down(s, off, 64);
            if (lane == 0) redw[tid >> 6] = s;
            __syncthreads();
            if (tid == 0) {
                double tot = 0.0;
#pragma unroll
                for (int wv = 0; wv < 8; ++wv) tot += redw[wv];
                cand_val[j] = tot + (double)b[cand_idx[j]];
            }
            __syncthreads();
        }
        if (tid == 0) {
            for (int j = 0; j < nc; ++j) cand_keep[j] = 0;
            for (int t = 0; t < need; ++t) {
                int best = -1;
                for (int j = 0; j < nc; ++j) {
                    if (cand_keep[j]) continue;
                    if (best < 0 || cand_val[j] > cand_val[best] ||
                        (cand_val[j] == cand_val[best] && cand_idx[j] < cand_idx[best]))
                        best = j;
                }
                cand_keep[best] = 1;
            }
        }
        __syncthreads();
        // rescan band elements: push kept, zero dropped (reg copies)
#pragma unroll
        for (int i = 0; i < 8; ++i)
#pragma unroll
            for (int c = 0; c < 4; ++c) {
                const float vv = v[i][c];
                if (vv >= loF && vv <= hiF && vv != 0.0f) {
                    const int e = (tid + i * 512) * 4 + c;
                    int slot = -1;
                    for (int j = 0; j < nc; ++j)
                        if (cand_idx[j] == e) { slot = j; break; }
                    if (slot >= 0) {
                        if (cand_keep[slot]) {
                            const int p = atomicAdd(&kcnt_s, 1);
                            if (p < KTOP) { kidx_s[p] = e; kval_s[p] = vv; }
                        } else {
                            v[i][c] = 0.0f;
                        }
                    }
                }
            }
        __syncthreads();
    } else {
        // keep all boundary candidates
#pragma unroll
        for (int i = 0; i < 8; ++i)
#pragma unroll
            for (int c = 0; c < 4; ++c) {
                const float vv = v[i][c];
                if (vv >= loF && vv <= hiF && vv != 0.0f) {
                    const int p = atomicAdd(&kcnt_s, 1);
                    if (p < KTOP) { kidx_s[p] = (tid + i * 512) * 4 + c; kval_s[p] = vv; }
                }
            }
        __syncthreads();
    }

    // ---- write pruned row back (vectorized) ----
#pragma unroll
    for (int i = 0; i < 8; ++i)
        ((f32x4*)hrow)[tid + i * 512] = v[i];

    if (use_list) {
        const int cnt = kcnt_s < KTOP ? kcnt_s : KTOP;
        if (tid == 0) kcnt_all[row] = cnt;
        for (int j = tid; j < cnt; j += 512) {
            kidx_all[(size_t)row * KTOP + j] = kidx_s[j];
            kval_all[(size_t)row * KTOP + j] = kval_s[j];
        }
    }
}

// ---------------------------------------------------------------------------
// Kernel 5a: sparse decode from compact list, bf16 weights (half the bytes).
// 2 rows per block; 128 threads/row, 16B weight loads, 32B output stores.
// ---------------------------------------------------------------------------
__global__ __launch_bounds__(256) void decode_list_bf16(const int* __restrict__ kcnt_all,
                                                        const int* __restrict__ kidx_all,
                                                        const float* __restrict__ kval_all,
                                                        const __hip_bfloat16* __restrict__ Wtb,
                                                        float* __restrict__ recon) {
    const int half = threadIdx.x >> 7;       // 0/1
    const int t    = threadIdx.x & 127;
    const int row  = blockIdx.x * 2 + half;

    __shared__ int   s_idx[2][KTOP];
    __shared__ float s_val[2][KTOP];
    __shared__ int   s_cnt[2];

    if (t == 0) s_cnt[half] = kcnt_all[row];
    if (t < KTOP) {
        s_idx[half][t] = kidx_all[(size_t)row * KTOP + t];
        s_val[half][t] = kval_all[(size_t)row * KTOP + t];
    }
    __syncthreads();
    const int cnt = s_cnt[half];

    const int d0 = t * 8;
    f32x4 acc0 = {0.f, 0.f, 0.f, 0.f}, acc1 = {0.f, 0.f, 0.f, 0.f};
#pragma unroll 2
    for (int j = 0; j < cnt; ++j) {
        const float vv = s_val[half][j];
        const bf16x8 wv = *(const bf16x8*)(Wtb + (size_t)s_idx[half][j] * DM + d0);
#pragma unroll
        for (int e = 0; e < 4; ++e) {
            const float w0 = __uint_as_float(((unsigned)(unsigned short)wv[e]) << 16);
            acc0[e] = fmaf(vv, w0, acc0[e]);
        }
#pragma unroll
        for (int e = 0; e < 4; ++e) {
            const float w1 = __uint_as_float(((unsigned)(unsigned short)wv[4 + e]) << 16);
            acc1[e] = fmaf(vv, w1, acc1[e]);
        }
    }
    float* out = recon + (size_t)row * DM + d0;
    *(f32x4*)out = acc0;
    *((f32x4*)out + 1) = acc1;
}

// ---------------------------------------------------------------------------
// Kernel 5b: fallback decode (scans h) if ws too small for the list path
// ---------------------------------------------------------------------------
__global__ __launch_bounds__(256) void decode(const float* __restrict__ h,
                                              const float* __restrict__ Wt,
                                              const float* __restrict__ Wdec,
                                              const int use_wt,
                                              float* __restrict__ recon) {
    const int row = blockIdx.x;
    const float* hrow = h + (size_t)row * DS;
    const int tid = threadIdx.x;

    __shared__ int   s_idx[KTOP];
    __shared__ float s_val[KTOP];
    __shared__ int   s_cnt;

    if (tid == 0) s_cnt = 0;
    __syncthreads();
    for (int i = tid; i < DS; i += 256) {
        const float v = hrow[i];
        if (v != 0.0f) {
            const int p = atomicAdd(&s_cnt, 1);
            if (p < KTOP) { s_idx[p] = i; s_val[p] = v; }
        }
    }
    __syncthreads();
    const int cnt = s_cnt < KTOP ? s_cnt : KTOP;

    const int d = tid * 4;
    float4 acc = {0.0f, 0.0f, 0.0f, 0.0f};
    if (use_wt) {
        for (int j = 0; j < cnt; ++j) {
            const float v = s_val[j];
            const float4 w = *(const float4*)&Wt[(size_t)s_idx[j] * DM + d];
            acc.x = fmaf(v, w.x, acc.x);
            acc.y = fmaf(v, w.y, acc.y);
            acc.z = fmaf(v, w.z, acc.z);
            acc.w = fmaf(v, w.w, acc.w);
        }
    } else {
        for (int j = 0; j < cnt; ++j) {
            const float v = s_val[j];
            const int s = s_idx[j];
            acc.x = fmaf(v, Wdec[(size_t)(d + 0) * DS + s], acc.x);
            acc.y = fmaf(v, Wdec[(size_t)(d + 1) * DS + s], acc.y);
            acc.z = fmaf(v, Wdec[(size_t)(d + 2) * DS + s], acc.z);
            acc.w = fmaf(v, Wdec[(size_t)(d + 3) * DS + s], acc.w);
        }
    }
    *(float4*)&recon[(size_t)row * DM + d] = acc;
}

// ---------------------------------------------------------------------------
extern "C" void kernel_launch(void* const* d_in, const int* in_sizes, int n_in,
                              void* d_out, int out_size, void* d_ws, size_t ws_size,
                              hipStream_t stream) {
    const float* x     = (const float*)d_in[0];
    const float* W_enc = (const float*)d_in[1];
    const float* b_enc = (const float*)d_in[2];
    const float* W_dec = (const float*)d_in[3];

    float* recon = (float*)d_out;
    float* h     = recon + (size_t)N_ROWS * DM;

    // workspace layout (unchanged FULL_NEED; k-lists alias the xhi/xlo region,
    // which is dead after enc_gemm_mfma completes)
    const size_t WT_BYTES = (size_t)DS * DM * sizeof(float);              // 64 MB
    const size_t XP_BYTES = (size_t)N_ROWS * DM * sizeof(__hip_bfloat16); // 16 MB
    const size_t WP_BYTES = (size_t)DS * DM * sizeof(__hip_bfloat16);     // 32 MB
    const size_t FULL_NEED = WT_BYTES + 2 * XP_BYTES + 2 * WP_BYTES;      // 160 MB
    const size_t KIDX_BYTES = (size_t)N_ROWS * KTOP * sizeof(int);        // 2 MB
    const size_t KVAL_BYTES = (size_t)N_ROWS * KTOP * sizeof(float);      // 2 MB

    char* wsb = (char*)d_ws;
    float* Wt = (float*)wsb;
    __hip_bfloat16* Wtb = (__hip_bfloat16*)wsb;   // bf16 transpose (list path)
    __hip_bfloat16* xhi = (__hip_bfloat16*)(wsb + WT_BYTES);
    __hip_bfloat16* xlo = (__hip_bfloat16*)(wsb + WT_BYTES + XP_BYTES);
    __hip_bfloat16* whi = (__hip_bfloat16*)(wsb + WT_BYTES + 2 * XP_BYTES);
    __hip_bfloat16* wlo = (__hip_bfloat16*)(wsb + WT_BYTES + 2 * XP_BYTES + WP_BYTES);
    // k-lists alias xhi/xlo (32 MB region, dead after the GEMM)
    int*   kidx_all = (int*)(wsb + WT_BYTES);
    float* kval_all = (float*)(wsb + WT_BYTES + KIDX_BYTES);
    int*   kcnt_all = (int*)(wsb + WT_BYTES + KIDX_BYTES + KVAL_BYTES);

    const int use_wt   = (ws_size >= WT_BYTES) ? 1 : 0;
    const int use_mfma = (ws_size >= FULL_NEED) ? 1 : 0;
    const int use_list = use_mfma;   // list fits in the dead xhi/xlo region

    if (use_list) {
        transpose_wdec_bf16<<<dim3(DS / 32, DM / 32), dim3(32, 8), 0, stream>>>(W_dec, Wtb);
    } else if (use_wt) {
        transpose_wdec<<<dim3(DS / 32, DM / 32), dim3(32, 8), 0, stream>>>(W_dec, Wt);
    }
    if (use_mfma) {
        const int nfrag_x = N_ROWS * DM / 8;   // 1048576
        const int nfrag_w = DS * DM / 8;       // 2097152
        pack_bf16<<<nfrag_x / 256, 256, 0, stream>>>(x, xhi, xlo, nfrag_x);
        pack_bf16<<<nfrag_w / 256, 256, 0, stream>>>(W_enc, whi, wlo, nfrag_w);
        enc_gemm_mfma<<<dim3(DS / 128, N_ROWS / 128), 256, 0, stream>>>(
            xhi, xlo, whi, wlo, b_enc, h);
    } else {
        enc_gemm<<<dim3(DS / TS, N_ROWS / TM), 256, 0, stream>>>(x, W_enc, b_enc, h);
    }
    topk_select<<<N_ROWS, 512, 0, stream>>>(x, W_enc, b_enc, h,
                                            kidx_all, kval_all, kcnt_all, use_list);
    if (use_list) {
        decode_list_bf16<<<N_ROWS / 2, 256, 0, stream>>>(kcnt_all, kidx_all, kval_all,
                                                         Wtb, recon);
    } else {
        decode<<<N_ROWS, 256, 0, stream>>>(h, Wt, W_dec, use_wt, recon);
    }
}

// Round 5
// 1720.476 us; speedup vs baseline: 1.5231x; 1.0541x over previous
//
#include <hip/hip_runtime.h>
#include <hip/hip_bf16.h>
#include <stdint.h>

#define N_ROWS 8192
#define DM     1024     // d_model
#define DS     16384    // d_sae
#define KTOP   64
#define CAND_CAP 256

typedef __attribute__((ext_vector_type(8))) short bf16x8;
typedef __attribute__((ext_vector_type(4))) float f32x4;

#define AS1 __attribute__((address_space(1)))
#define AS3 __attribute__((address_space(3)))

// ---------------------------------------------------------------------------
// Kernel 1: transpose W_dec [DM x DS] -> Wt fp32 [DS x DM] (fallback path)
// ---------------------------------------------------------------------------
__global__ __launch_bounds__(256) void transpose_wdec(const float* __restrict__ W,
                                                      float* __restrict__ Wt) {
    __shared__ float tile[32][33];
    const int tx = threadIdx.x;        // 0..31
    const int ty = threadIdx.y;        // 0..7
    const int s0 = blockIdx.x * 32;    // along DS
    const int d0 = blockIdx.y * 32;    // along DM
#pragma unroll
    for (int j = 0; j < 32; j += 8)
        tile[ty + j][tx] = W[(size_t)(d0 + ty + j) * DS + (s0 + tx)];
    __syncthreads();
#pragma unroll
    for (int j = 0; j < 32; j += 8)
        Wt[(size_t)(s0 + ty + j) * DM + (d0 + tx)] = tile[tx][ty + j];
}

// ---------------------------------------------------------------------------
// Kernel 1b: transpose W_dec -> Wtb bf16 [DS x DM] (halves decode gather bytes)
// ---------------------------------------------------------------------------
__global__ __launch_bounds__(256) void transpose_wdec_bf16(const float* __restrict__ W,
                                                           __hip_bfloat16* __restrict__ Wtb) {
    __shared__ float tile[32][33];
    const int tx = threadIdx.x;        // 0..31
    const int ty = threadIdx.y;        // 0..7
    const int tid = ty * 32 + tx;
    const int s0 = blockIdx.x * 32;    // along DS
    const int d0 = blockIdx.y * 32;    // along DM
#pragma unroll
    for (int j = 0; j < 32; j += 8)
        tile[ty + j][tx] = W[(size_t)(d0 + ty + j) * DS + (s0 + tx)];
    __syncthreads();
    const int cp = tid & 15;           // column pair within d
    const int rr = tid >> 4;           // 0..15 (s rows)
#pragma unroll
    for (int j = 0; j < 32; j += 16) {
        const int sl = rr + j;
        __hip_bfloat162 pr;
        pr.x = __float2bfloat16(tile[cp * 2 + 0][sl]);
        pr.y = __float2bfloat16(tile[cp * 2 + 1][sl]);
        *(__hip_bfloat162*)(Wtb + (size_t)(s0 + sl) * DM + d0 + cp * 2) = pr;
    }
}

// ---------------------------------------------------------------------------
// Kernel 2: fp32 -> bf16 (round-to-nearest) in MFMA-staging packed layout.
// Chunk layout (per 128-row block rb, per 32-k slab ks): 8 chunks of 1KB;
// chunk g holds rows g*16..g*16+15; lane l=(q*16+m) stores 8 bf16 = row
// (g*16+m), k = ks*32 + q*8 .. +7, at elem offset
// (rb*32+ks)*4096 + g*512 + l*8.
// ---------------------------------------------------------------------------
__global__ __launch_bounds__(256) void pack_hi(const float* __restrict__ src,
                                               __hip_bfloat16* __restrict__ hi,
                                               int nfrag) {
    const int t = blockIdx.x * 256 + threadIdx.x;
    if (t >= nfrag) return;
    const int l  = t & 63;
    const int g  = (t >> 6) & 7;
    const int ks = (t >> 9) & 31;
    const int rb = t >> 14;
    const int m = l & 15, q = l >> 4;
    const int row = rb * 128 + g * 16 + m;
    const int k0  = ks * 32 + q * 8;
    const float* s = src + (size_t)row * DM + k0;
#pragma unroll
    for (int j = 0; j < 8; ++j)
        hi[(size_t)t * 8 + j] = __float2bfloat16(s[j]);
}

// ---------------------------------------------------------------------------
// Kernel 3: encoder GEMM, pure bf16 single product (error absorbed by the
// widened topk boundary band + fp64 resolve). m97-shape: 128x128 tile,
// BK=64 (two contiguous 32-k slabs), 4 waves, 32KB LDS, width-16
// global_load_lds. Per K-step/wave: 8 gload + 16 ds_read_b128 + 32 MFMA.
// ---------------------------------------------------------------------------
#define LDS_A 0
#define LDS_B 16384

__global__ __launch_bounds__(256) void enc_gemm_bf16(
        const __hip_bfloat16* __restrict__ xh, const __hip_bfloat16* __restrict__ wh,
        const float* __restrict__ bias, float* __restrict__ h) {
    __shared__ __align__(16) char lds[32768];
    const int tid  = threadIdx.x;
    const int lane = tid & 63;
    const int w    = tid >> 6;           // wave 0..3
    const int mb   = blockIdx.y;         // 0..63   (x row-block)
    const int sb   = blockIdx.x;         // 0..127  (W row-block)

    f32x4 acc[4][4];
#pragma unroll
    for (int i = 0; i < 4; ++i)
#pragma unroll
        for (int j = 0; j < 4; ++j) acc[i][j] = (f32x4){0.f, 0.f, 0.f, 0.f};

    const int gm = (w >> 1) * 4;   // m quadrant
    const int gs = (w & 1) * 4;    // s quadrant

    for (int k2 = 0; k2 < 16; ++k2) {      // BK=64: slabs 2*k2, 2*k2+1
        const size_t abase = ((size_t)mb * 32 + k2 * 2) * 4096;
        const size_t bbase = ((size_t)sb * 32 + k2 * 2) * 4096;
        // 16 A-chunks + 16 B-chunks of 1KB; each wave stages 4+4
#pragma unroll
        for (int c = 0; c < 4; ++c) {
            const int g = w * 4 + c;       // 0..15 (g<8 slab0, g>=8 slab1)
            __builtin_amdgcn_global_load_lds((const AS1 void*)(xh + abase + g * 512 + lane * 8),
                                             (AS3 void*)(lds + LDS_A + g * 1024), 16, 0, 0);
            __builtin_amdgcn_global_load_lds((const AS1 void*)(wh + bbase + g * 512 + lane * 8),
                                             (AS3 void*)(lds + LDS_B + g * 1024), 16, 0, 0);
        }
        __syncthreads();   // drains vmcnt -> LDS tiles valid

        bf16x8 a0[4], a1[4], b0[4], b1[4];
#pragma unroll
        for (int t = 0; t < 4; ++t) {
            a0[t] = *((const bf16x8*)(lds + LDS_A + (gm + t) * 1024) + lane);
            a1[t] = *((const bf16x8*)(lds + LDS_A + 8192 + (gm + t) * 1024) + lane);
            b0[t] = *((const bf16x8*)(lds + LDS_B + (gs + t) * 1024) + lane);
            b1[t] = *((const bf16x8*)(lds + LDS_B + 8192 + (gs + t) * 1024) + lane);
        }
#pragma unroll
        for (int tm = 0; tm < 4; ++tm)
#pragma unroll
            for (int ts = 0; ts < 4; ++ts) {
                acc[tm][ts] = __builtin_amdgcn_mfma_f32_16x16x32_bf16(a0[tm], b0[ts], acc[tm][ts], 0, 0, 0);
                acc[tm][ts] = __builtin_amdgcn_mfma_f32_16x16x32_bf16(a1[tm], b1[ts], acc[tm][ts], 0, 0, 0);
            }
        __syncthreads();
    }

    // epilogue: C/D layout col=lane&15 (s), row=(lane>>4)*4+reg (m)
    const int m0 = mb * 128 + (w >> 1) * 64 + (lane >> 4) * 4;
    const int s0 = sb * 128 + (w & 1) * 64 + (lane & 15);
#pragma unroll
    for (int ts = 0; ts < 4; ++ts) {
        const int s = s0 + ts * 16;
        const float bb = bias[s];
#pragma unroll
        for (int tm = 0; tm < 4; ++tm) {
            const int m = m0 + tm * 16;
#pragma unroll
            for (int r = 0; r < 4; ++r)
                h[(size_t)(m + r) * DS + s] = fmaxf(acc[tm][ts][r] + bb, 0.0f);
        }
    }
}

// ---------------------------------------------------------------------------
// Kernel 2b: fp32 fallback GEMM if ws too small for packing
// ---------------------------------------------------------------------------
#define TM 128
#define TS 128
#define TK 16
#define LDP (TM + 4)

__global__ __launch_bounds__(256) void enc_gemm(const float* __restrict__ x,
                                                const float* __restrict__ W,
                                                const float* __restrict__ b,
                                                float* __restrict__ h) {
    __shared__ float As[TK][LDP];
    __shared__ float Ws[TK][LDP];
    const int tid  = threadIdx.x;
    const int tx   = tid & 15;
    const int ty   = tid >> 4;
    const int row0 = blockIdx.y * TM;
    const int s0   = blockIdx.x * TS;
    const int lm = tid >> 2;
    const int lk = (tid & 3) * 4;

    float acc[8][8];
#pragma unroll
    for (int i = 0; i < 8; ++i)
#pragma unroll
        for (int j = 0; j < 8; ++j) acc[i][j] = 0.0f;

    float4 a0 = *(const float4*)&x[(size_t)(row0 + lm) * DM + lk];
    float4 a1 = *(const float4*)&x[(size_t)(row0 + lm + 64) * DM + lk];
    float4 w0 = *(const float4*)&W[(size_t)(s0 + lm) * DM + lk];
    float4 w1 = *(const float4*)&W[(size_t)(s0 + lm + 64) * DM + lk];

    for (int k0 = 0; k0 < DM; k0 += TK) {
        __syncthreads();
        As[lk + 0][lm] = a0.x; As[lk + 1][lm] = a0.y;
        As[lk + 2][lm] = a0.z; As[lk + 3][lm] = a0.w;
        As[lk + 0][lm + 64] = a1.x; As[lk + 1][lm + 64] = a1.y;
        As[lk + 2][lm + 64] = a1.z; As[lk + 3][lm + 64] = a1.w;
        Ws[lk + 0][lm] = w0.x; Ws[lk + 1][lm] = w0.y;
        Ws[lk + 2][lm] = w0.z; Ws[lk + 3][lm] = w0.w;
        Ws[lk + 0][lm + 64] = w1.x; Ws[lk + 1][lm + 64] = w1.y;
        Ws[lk + 2][lm + 64] = w1.z; Ws[lk + 3][lm + 64] = w1.w;
        __syncthreads();
        const int kn = (k0 + TK < DM) ? (k0 + TK) : k0;
        a0 = *(const float4*)&x[(size_t)(row0 + lm) * DM + kn + lk];
        a1 = *(const float4*)&x[(size_t)(row0 + lm + 64) * DM + kn + lk];
        w0 = *(const float4*)&W[(size_t)(s0 + lm) * DM + kn + lk];
        w1 = *(const float4*)&W[(size_t)(s0 + lm + 64) * DM + kn + lk];
#pragma unroll
        for (int kk = 0; kk < TK; ++kk) {
            float4 aA = *(const float4*)&As[kk][ty * 4];
            float4 aB = *(const float4*)&As[kk][ty * 4 + 64];
            float4 wA = *(const float4*)&Ws[kk][tx * 4];
            float4 wB = *(const float4*)&Ws[kk][tx * 4 + 64];
            float am[8] = {aA.x, aA.y, aA.z, aA.w, aB.x, aB.y, aB.z, aB.w};
            float wn[8] = {wA.x, wA.y, wA.z, wA.w, wB.x, wB.y, wB.z, wB.w};
#pragma unroll
            for (int i = 0; i < 8; ++i)
#pragma unroll
                for (int j = 0; j < 8; ++j)
                    acc[i][j] = fmaf(am[i], wn[j], acc[i][j]);
        }
    }
    float blo[4], bhi[4];
#pragma unroll
    for (int u = 0; u < 4; ++u) {
        blo[u] = b[s0 + tx * 4 + u];
        bhi[u] = b[s0 + 64 + tx * 4 + u];
    }
#pragma unroll
    for (int i = 0; i < 8; ++i) {
        const int r = (i < 4) ? (row0 + ty * 4 + i) : (row0 + 64 + ty * 4 + (i - 4));
        float4 lo, hi;
        lo.x = fmaxf(acc[i][0] + blo[0], 0.0f);
        lo.y = fmaxf(acc[i][1] + blo[1], 0.0f);
        lo.z = fmaxf(acc[i][2] + blo[2], 0.0f);
        lo.w = fmaxf(acc[i][3] + blo[3], 0.0f);
        hi.x = fmaxf(acc[i][4] + bhi[0], 0.0f);
        hi.y = fmaxf(acc[i][5] + bhi[1], 0.0f);
        hi.z = fmaxf(acc[i][6] + bhi[2], 0.0f);
        hi.w = fmaxf(acc[i][7] + bhi[3], 0.0f);
        *(float4*)&h[(size_t)r * DS + s0 + tx * 4]      = lo;
        *(float4*)&h[(size_t)r * DS + s0 + 64 + tx * 4] = hi;
    }
}

// ---------------------------------------------------------------------------
// radix bin selection by one wave (bins ascending in value)
// ---------------------------------------------------------------------------
template <int PER_LANE>
__device__ inline void radix_select(const unsigned* __restrict__ hist,
                                    int lane, int kv,
                                    unsigned* sel_bin, int* sel_k, int* lt_flag) {
    unsigned cnt[PER_LANE];
    unsigned loc = 0;
#pragma unroll
    for (int j = 0; j < PER_LANE; ++j) { cnt[j] = hist[lane * PER_LANE + j]; loc += cnt[j]; }
    unsigned sfx = loc;
#pragma unroll
    for (int off = 1; off < 64; off <<= 1) {
        const unsigned o = __shfl_down(sfx, off, 64);
        if (lane + off < 64) sfx += o;
    }
    if (lt_flag != nullptr && lane == 0 && sfx < (unsigned)kv) *lt_flag = 1;
    unsigned above = sfx - loc;
#pragma unroll
    for (int j = PER_LANE - 1; j >= 0; --j) {
        const unsigned c = cnt[j];
        if (above < (unsigned)kv && above + c >= (unsigned)kv) {
            *sel_k = kv - (int)above;
            *sel_bin = (unsigned)(lane * PER_LANE + j);
        }
        above += c;
    }
}

// ---------------------------------------------------------------------------
// Kernel 4: register-resident per-row top-64 select + prune.
// Band widened to +/-7e-3 (>= 2x max pure-bf16 GEMM error); membership inside
// the band is resolved EXACTLY in fp64, so top-64 selection is unaffected by
// the encoder precision drop.
// ---------------------------------------------------------------------------
__global__ __launch_bounds__(512) void topk_select(const float* __restrict__ x,
                                                   const float* __restrict__ W,
                                                   const float* __restrict__ b,
                                                   float* __restrict__ h,
                                                   int* __restrict__ kidx_all,
                                                   float* __restrict__ kval_all,
                                                   int* __restrict__ kcnt_all,
                                                   const int use_list) {
    const int row = blockIdx.x;
    float* hrow = h + (size_t)row * DS;
    const int tid  = threadIdx.x;
    const int lane = tid & 63;

    __shared__ unsigned hist[2048];
    __shared__ unsigned sel_bin;
    __shared__ int sel_k;
    __shared__ int lt_flag;
    __shared__ int kidx_s[KTOP];
    __shared__ float kval_s[KTOP];
    __shared__ int kcnt_s;
    __shared__ int cand_idx[CAND_CAP];
    __shared__ int cand_cnt;
    __shared__ double cand_val[CAND_CAP];
    __shared__ unsigned char cand_keep[CAND_CAP];
    __shared__ double redw[8];

    hist[tid] = 0u; hist[tid + 512] = 0u; hist[tid + 1024] = 0u; hist[tid + 1536] = 0u;
    if (tid == 0) { sel_k = KTOP; kcnt_s = 0; cand_cnt = 0; lt_flag = 0; }
    __syncthreads();

    // ---- load row into registers + pass-1 histogram (top 11 bits) ----
    const f32x4* src = (const f32x4*)hrow;
    f32x4 v[8];
#pragma unroll
    for (int i = 0; i < 8; ++i) v[i] = src[tid + i * 512];
#pragma unroll
    for (int i = 0; i < 8; ++i)
#pragma unroll
        for (int c = 0; c < 4; ++c) {
            const unsigned u = __float_as_uint(v[i][c]);
            if (u != 0u) atomicAdd(&hist[u >> 21], 1u);
        }
    __syncthreads();
    if (tid < 64) radix_select<32>(hist, lane, KTOP, &sel_bin, &sel_k, &lt_flag);
    __syncthreads();

    // ---- fewer than KTOP positives: keep everything ----
    if (lt_flag != 0) {
        if (use_list) {
#pragma unroll
            for (int i = 0; i < 8; ++i)
#pragma unroll
                for (int c = 0; c < 4; ++c) {
                    const float vv = v[i][c];
                    if (vv != 0.0f) {
                        const int p = atomicAdd(&kcnt_s, 1);
                        if (p < KTOP) { kidx_s[p] = (tid + i * 512) * 4 + c; kval_s[p] = vv; }
                    }
                }
            __syncthreads();
            const int cnt = kcnt_s < KTOP ? kcnt_s : KTOP;
            if (tid == 0) kcnt_all[row] = cnt;
            for (int j = tid; j < cnt; j += 512) {
                kidx_all[(size_t)row * KTOP + j] = kidx_s[j];
                kval_all[(size_t)row * KTOP + j] = kval_s[j];
            }
        }
        return;
    }

    const unsigned b1 = sel_bin;

    // ---- pass 2: next 11 bits ----
    hist[tid] = 0u; hist[tid + 512] = 0u; hist[tid + 1024] = 0u; hist[tid + 1536] = 0u;
    __syncthreads();
#pragma unroll
    for (int i = 0; i < 8; ++i)
#pragma unroll
        for (int c = 0; c < 4; ++c) {
            const unsigned u = __float_as_uint(v[i][c]);
            if (u != 0u && (u >> 21) == b1) atomicAdd(&hist[(u >> 10) & 0x7FFu], 1u);
        }
    __syncthreads();
    {
        const int kv = sel_k;
        if (tid < 64) radix_select<32>(hist, lane, kv, &sel_bin, &sel_k, nullptr);
    }
    __syncthreads();
    const unsigned pfx22 = (b1 << 11) | sel_bin;

    // ---- pass 3: final 10 bits ----
    hist[tid] = 0u; hist[tid + 512] = 0u;
    __syncthreads();
#pragma unroll
    for (int i = 0; i < 8; ++i)
#pragma unroll
        for (int c = 0; c < 4; ++c) {
            const unsigned u = __float_as_uint(v[i][c]);
            if (u != 0u && (u >> 10) == pfx22) atomicAdd(&hist[u & 0x3FFu], 1u);
        }
    __syncthreads();
    {
        const int kv = sel_k;
        if (tid < 64) radix_select<16>(hist, lane, kv, &sel_bin, &sel_k, nullptr);
    }
    __syncthreads();
    const unsigned T = (pfx22 << 10) | sel_bin;

    const float Tv = __uint_as_float(T);
    const float delta = (Tv > 0.01f) ? 7.0e-3f : 0.0f;   // >= 2x max bf16 GEMM err
    const float loF = Tv - delta;
    const float hiF = Tv + delta;

    // ---- classify from registers ----
#pragma unroll
    for (int i = 0; i < 8; ++i)
#pragma unroll
        for (int c = 0; c < 4; ++c) {
            const float vv = v[i][c];
            if (vv > hiF) {
                const int p = atomicAdd(&kcnt_s, 1);
                if (p < KTOP) { kidx_s[p] = (tid + i * 512) * 4 + c; kval_s[p] = vv; }
            } else if (vv >= loF) {
                const int p = atomicAdd(&cand_cnt, 1);
                if (p < CAND_CAP) cand_idx[p] = (tid + i * 512) * 4 + c;
            } else if (vv != 0.0f) {
                v[i][c] = 0.0f;
            }
        }
    __syncthreads();

    const int sure = kcnt_s < KTOP ? kcnt_s : KTOP;
    const int nc = cand_cnt < CAND_CAP ? cand_cnt : CAND_CAP;
    const int need = KTOP - sure;

    if (nc > need) {
        // fp64 exact recompute of boundary band
        const float* xrow = x + (size_t)row * DM;
        const int kk = tid * 2;
        const double x0 = (double)xrow[kk], x1 = (double)xrow[kk + 1];
        for (int j = 0; j < nc; ++j) {
            const float* wrow = W + (size_t)cand_idx[j] * DM;
            double s = x0 * (double)wrow[kk] + x1 * (double)wrow[kk + 1];
#pragma unroll
            for (int off = 32; off > 0; off >>= 1)
                s += __shfl_down(s, off, 64);
            if (lane == 0) redw[tid >> 6] = s;
            __syncthreads();
            if (tid == 0) {
                double tot = 0.0;
#pragma unroll
                for (int wv = 0; wv < 8; ++wv) tot += redw[wv];
                cand_val[j] = tot + (double)b[cand_idx[j]];
            }
            __syncthreads();
        }
        if (tid == 0) {
            for (int j = 0; j < nc; ++j) cand_keep[j] = 0;
            for (int t = 0; t < need; ++t) {
                int best = -1;
                for (int j = 0; j < nc; ++j) {
                    if (cand_keep[j]) continue;
                    if (best < 0 || cand_val[j] > cand_val[best] ||
                        (cand_val[j] == cand_val[best] && cand_idx[j] < cand_idx[best]))
                        best = j;
                }
                cand_keep[best] = 1;
            }
        }
        __syncthreads();
#pragma unroll
        for (int i = 0; i < 8; ++i)
#pragma unroll
            for (int c = 0; c < 4; ++c) {
                const float vv = v[i][c];
                if (vv >= loF && vv <= hiF && vv != 0.0f) {
                    const int e = (tid + i * 512) * 4 + c;
                    int slot = -1;
                    for (int j = 0; j < nc; ++j)
                        if (cand_idx[j] == e) { slot = j; break; }
                    if (slot >= 0) {
                        if (cand_keep[slot]) {
                            const int p = atomicAdd(&kcnt_s, 1);
                            if (p < KTOP) { kidx_s[p] = e; kval_s[p] = vv; }
                        } else {
                            v[i][c] = 0.0f;
                        }
                    }
                }
            }
        __syncthreads();
    } else {
#pragma unroll
        for (int i = 0; i < 8; ++i)
#pragma unroll
            for (int c = 0; c < 4; ++c) {
                const float vv = v[i][c];
                if (vv >= loF && vv <= hiF && vv != 0.0f) {
                    const int p = atomicAdd(&kcnt_s, 1);
                    if (p < KTOP) { kidx_s[p] = (tid + i * 512) * 4 + c; kval_s[p] = vv; }
                }
            }
        __syncthreads();
    }

    // ---- write pruned row back (vectorized) ----
#pragma unroll
    for (int i = 0; i < 8; ++i)
        ((f32x4*)hrow)[tid + i * 512] = v[i];

    if (use_list) {
        const int cnt = kcnt_s < KTOP ? kcnt_s : KTOP;
        if (tid == 0) kcnt_all[row] = cnt;
        for (int j = tid; j < cnt; j += 512) {
            kidx_all[(size_t)row * KTOP + j] = kidx_s[j];
            kval_all[(size_t)row * KTOP + j] = kval_s[j];
        }
    }
}

// ---------------------------------------------------------------------------
// Kernel 5a: sparse decode from compact list, bf16 weights
// ---------------------------------------------------------------------------
__global__ __launch_bounds__(256) void decode_list_bf16(const int* __restrict__ kcnt_all,
                                                        const int* __restrict__ kidx_all,
                                                        const float* __restrict__ kval_all,
                                                        const __hip_bfloat16* __restrict__ Wtb,
                                                        float* __restrict__ recon) {
    const int half = threadIdx.x >> 7;       // 0/1
    const int t    = threadIdx.x & 127;
    const int row  = blockIdx.x * 2 + half;

    __shared__ int   s_idx[2][KTOP];
    __shared__ float s_val[2][KTOP];
    __shared__ int   s_cnt[2];

    if (t == 0) s_cnt[half] = kcnt_all[row];
    if (t < KTOP) {
        s_idx[half][t] = kidx_all[(size_t)row * KTOP + t];
        s_val[half][t] = kval_all[(size_t)row * KTOP + t];
    }
    __syncthreads();
    const int cnt = s_cnt[half];

    const int d0 = t * 8;
    f32x4 acc0 = {0.f, 0.f, 0.f, 0.f}, acc1 = {0.f, 0.f, 0.f, 0.f};
#pragma unroll 2
    for (int j = 0; j < cnt; ++j) {
        const float vv = s_val[half][j];
        const bf16x8 wv = *(const bf16x8*)(Wtb + (size_t)s_idx[half][j] * DM + d0);
#pragma unroll
        for (int e = 0; e < 4; ++e) {
            const float w0 = __uint_as_float(((unsigned)(unsigned short)wv[e]) << 16);
            acc0[e] = fmaf(vv, w0, acc0[e]);
        }
#pragma unroll
        for (int e = 0; e < 4; ++e) {
            const float w1 = __uint_as_float(((unsigned)(unsigned short)wv[4 + e]) << 16);
            acc1[e] = fmaf(vv, w1, acc1[e]);
        }
    }
    float* out = recon + (size_t)row * DM + d0;
    *(f32x4*)out = acc0;
    *((f32x4*)out + 1) = acc1;
}

// ---------------------------------------------------------------------------
// Kernel 5b: fallback decode (scans h) if ws too small for the list path
// ---------------------------------------------------------------------------
__global__ __launch_bounds__(256) void decode(const float* __restrict__ h,
                                              const float* __restrict__ Wt,
                                              const float* __restrict__ Wdec,
                                              const int use_wt,
                                              float* __restrict__ recon) {
    const int row = blockIdx.x;
    const float* hrow = h + (size_t)row * DS;
    const int tid = threadIdx.x;

    __shared__ int   s_idx[KTOP];
    __shared__ float s_val[KTOP];
    __shared__ int   s_cnt;

    if (tid == 0) s_cnt = 0;
    __syncthreads();
    for (int i = tid; i < DS; i += 256) {
        const float v = hrow[i];
        if (v != 0.0f) {
            const int p = atomicAdd(&s_cnt, 1);
            if (p < KTOP) { s_idx[p] = i; s_val[p] = v; }
        }
    }
    __syncthreads();
    const int cnt = s_cnt < KTOP ? s_cnt : KTOP;

    const int d = tid * 4;
    float4 acc = {0.0f, 0.0f, 0.0f, 0.0f};
    if (use_wt) {
        for (int j = 0; j < cnt; ++j) {
            const float v = s_val[j];
            const float4 w = *(const float4*)&Wt[(size_t)s_idx[j] * DM + d];
            acc.x = fmaf(v, w.x, acc.x);
            acc.y = fmaf(v, w.y, acc.y);
            acc.z = fmaf(v, w.z, acc.z);
            acc.w = fmaf(v, w.w, acc.w);
        }
    } else {
        for (int j = 0; j < cnt; ++j) {
            const float v = s_val[j];
            const int s = s_idx[j];
            acc.x = fmaf(v, Wdec[(size_t)(d + 0) * DS + s], acc.x);
            acc.y = fmaf(v, Wdec[(size_t)(d + 1) * DS + s], acc.y);
            acc.z = fmaf(v, Wdec[(size_t)(d + 2) * DS + s], acc.z);
            acc.w = fmaf(v, Wdec[(size_t)(d + 3) * DS + s], acc.w);
        }
    }
    *(float4*)&recon[(size_t)row * DM + d] = acc;
}

// ---------------------------------------------------------------------------
extern "C" void kernel_launch(void* const* d_in, const int* in_sizes, int n_in,
                              void* d_out, int out_size, void* d_ws, size_t ws_size,
                              hipStream_t stream) {
    const float* x     = (const float*)d_in[0];
    const float* W_enc = (const float*)d_in[1];
    const float* b_enc = (const float*)d_in[2];
    const float* W_dec = (const float*)d_in[3];

    float* recon = (float*)d_out;
    float* h     = recon + (size_t)N_ROWS * DM;

    // workspace layout (hi-only packing: total need ~116 MB)
    const size_t WT_BYTES = (size_t)DS * DM * sizeof(float);              // 64 MB (Wt fp32 or Wtb bf16)
    const size_t XP_BYTES = (size_t)N_ROWS * DM * sizeof(__hip_bfloat16); // 16 MB
    const size_t WP_BYTES = (size_t)DS * DM * sizeof(__hip_bfloat16);     // 32 MB
    const size_t KIDX_BYTES = (size_t)N_ROWS * KTOP * sizeof(int);        // 2 MB
    const size_t KVAL_BYTES = (size_t)N_ROWS * KTOP * sizeof(float);      // 2 MB
    const size_t KCNT_BYTES = (size_t)N_ROWS * sizeof(int);               // 32 KB
    const size_t FAST_NEED = WT_BYTES + XP_BYTES + WP_BYTES
                           + KIDX_BYTES + KVAL_BYTES + KCNT_BYTES;        // ~116 MB

    char* wsb = (char*)d_ws;
    float* Wt = (float*)wsb;
    __hip_bfloat16* Wtb = (__hip_bfloat16*)wsb;
    __hip_bfloat16* xhi = (__hip_bfloat16*)(wsb + WT_BYTES);
    __hip_bfloat16* whi = (__hip_bfloat16*)(wsb + WT_BYTES + XP_BYTES);
    int*   kidx_all = (int*)(wsb + WT_BYTES + XP_BYTES + WP_BYTES);
    float* kval_all = (float*)(wsb + WT_BYTES + XP_BYTES + WP_BYTES + KIDX_BYTES);
    int*   kcnt_all = (int*)(wsb + WT_BYTES + XP_BYTES + WP_BYTES + KIDX_BYTES + KVAL_BYTES);

    const int use_wt   = (ws_size >= WT_BYTES) ? 1 : 0;
    const int use_fast = (ws_size >= FAST_NEED) ? 1 : 0;

    if (use_fast) {
        transpose_wdec_bf16<<<dim3(DS / 32, DM / 32), dim3(32, 8), 0, stream>>>(W_dec, Wtb);
    } else if (use_wt) {
        transpose_wdec<<<dim3(DS / 32, DM / 32), dim3(32, 8), 0, stream>>>(W_dec, Wt);
    }
    if (use_fast) {
        const int nfrag_x = N_ROWS * DM / 8;   // 1048576
        const int nfrag_w = DS * DM / 8;       // 2097152
        pack_hi<<<nfrag_x / 256, 256, 0, stream>>>(x, xhi, nfrag_x);
        pack_hi<<<nfrag_w / 256, 256, 0, stream>>>(W_enc, whi, nfrag_w);
        enc_gemm_bf16<<<dim3(DS / 128, N_ROWS / 128), 256, 0, stream>>>(
            xhi, whi, b_enc, h);
    } else {
        enc_gemm<<<dim3(DS / TS, N_ROWS / TM), 256, 0, stream>>>(x, W_enc, b_enc, h);
    }
    topk_select<<<N_ROWS, 512, 0, stream>>>(x, W_enc, b_enc, h,
                                            kidx_all, kval_all, kcnt_all, use_fast);
    if (use_fast) {
        decode_list_bf16<<<N_ROWS / 2, 256, 0, stream>>>(kcnt_all, kidx_all, kval_all,
                                                         Wtb, recon);
    } else {
        decode<<<N_ROWS, 256, 0, stream>>>(h, Wt, W_dec, use_wt, recon);
    }
}